// Round 8
// baseline (446.170 us; speedup 1.0000x reference)
//
#include <hip/hip_runtime.h>
#include <math.h>

// GRUDetector: B=1024, T=512, F=64, H=128, gates (r,z,n), + MLP head (H->32->1).
// R8: R7 (331us = 1622 cyc/step) decomposes as gates ~600 + u-DS 576 (8 waves x
// 6KB) + AGPR<->VGPR weight copies ~288 ("+v" pin forced VGPR materialization;
// VGPR=88 => weights lived in AGPRs) + MFMA 180. Fix: (1) 4 waves (256 thr),
// wave owns 96 gate rows (s=0,1) -> u-DS halves to 24KB/step; (2) pin W_hh
// frags "+a" (MFMA reads A-operands from AGPR natively) and W_ih frags "+v",
// pins in-loop (R7's remat blocker); waves_per_eu(1,1) -> 256v+256a budget.
// Skeleton: U dbuf, 1 barrier/step, lookahead-2 x prefetch (R7, absmax 9.8e-4).

#define Bsz  1024
#define Tlen 512
#define Fdim 64
#define Hdim 128
#define Gdim 384
#define NB   16
#define NTHR 256
#define NBLK (Bsz / NB)   // 64

typedef __attribute__((ext_vector_type(8))) _Float16 f16x8;
typedef __attribute__((ext_vector_type(4))) _Float16 f16x4;
typedef __attribute__((ext_vector_type(4))) float    f32x4;

__device__ __forceinline__ float fast_sigmoid(float v) {
    return __builtin_amdgcn_rcpf(1.f + __expf(-v));
}
__device__ __forceinline__ float fast_tanh(float v) {
    return 1.f - 2.f * __builtin_amdgcn_rcpf(__expf(2.f * v) + 1.f);
}

__global__ void
__attribute__((amdgpu_flat_work_group_size(NTHR, NTHR), amdgpu_waves_per_eu(1, 1)))
gru_mfma(const float* __restrict__ x,
         const float* __restrict__ W_ih, const float* __restrict__ W_hh,
         const float* __restrict__ b_ih, const float* __restrict__ b_hh,
         const float* __restrict__ W1, const float* __restrict__ b1,
         const float* __restrict__ W2, const float* __restrict__ b2,
         float* __restrict__ out)
{
    __shared__ __align__(16) _Float16 WH[24 * 4 * 4 * 128];  // 98,304 B
    __shared__ __align__(16) _Float16 WI[24 * 2 * 4 * 128];  // 49,152 B
    __shared__ __align__(16) _Float16 U0[6 * 4 * 16 * 8];    //  6,144 B
    __shared__ __align__(16) _Float16 U1[6 * 4 * 16 * 8];    //  6,144 B  (156 KB)

    const int tid  = threadIdx.x;
    const int w    = tid >> 6;        // wave 0..3: gate-row range 96w..96w+95
    const int l    = tid & 63;
    const int q    = l >> 4;
    const int bcol = l & 15;
    const int b0   = blockIdx.x * NB;

    // ---- stage W_hh, W_ih into LDS in A-fragment layout (one-time)
    for (int i = tid; i < Gdim * Hdim; i += NTHR) {
        int gr = i >> 7, k = i & 127;
        int idx = (((gr >> 4) * 4 + (k >> 5)) * 4 + ((k & 31) >> 3)) * 128
                + (gr & 15) * 8 + (k & 7);
        WH[idx] = (_Float16)W_hh[i];
    }
    for (int i = tid; i < Gdim * Fdim; i += NTHR) {
        int gr = i >> 6, k = i & 63;
        int idx = (((gr >> 4) * 2 + (k >> 5)) * 4 + ((k & 31) >> 3)) * 128
                + (gr & 15) * 8 + (k & 7);
        WI[idx] = (_Float16)W_ih[i];
    }
    for (int i = tid; i < 2048; i += NTHR) U0[i] = (_Float16)0.f;  // h(0) = 0
    {   // stage x(t=0): 4 halfwords per thread
        int e = tid * 4, bx_ = e >> 6, j = e & 63;
        float4 xv = *reinterpret_cast<const float4*>(
            &x[((size_t)(b0 + bx_) * Tlen + 0) * Fdim + j]);
        int kk = 128 + j;   // j%4==0 -> kk..kk+3 stay in one 8-group
        int idx = (((kk >> 5) * 4 + ((kk & 31) >> 3)) * 16 + bx_) * 8 + (kk & 7);
        f16x4 xq = {(_Float16)xv.x, (_Float16)xv.y, (_Float16)xv.z, (_Float16)xv.w};
        *reinterpret_cast<f16x4*>(&U0[idx]) = xq;
    }

    // ---- per-lane biases for s=0,1 (gate rows 16*(2w+s)+4q+j)
#define GR(S, J) (16 * (2 * w + (S)) + 4 * q + (J))
    f32x4 brv0 = {b_ih[GR(0,0)] + b_hh[GR(0,0)], b_ih[GR(0,1)] + b_hh[GR(0,1)],
                  b_ih[GR(0,2)] + b_hh[GR(0,2)], b_ih[GR(0,3)] + b_hh[GR(0,3)]};
    f32x4 brv1 = {b_ih[GR(1,0)] + b_hh[GR(1,0)], b_ih[GR(1,1)] + b_hh[GR(1,1)],
                  b_ih[GR(1,2)] + b_hh[GR(1,2)], b_ih[GR(1,3)] + b_hh[GR(1,3)]};
    f32x4 bzv0 = {b_ih[Hdim+GR(0,0)] + b_hh[Hdim+GR(0,0)], b_ih[Hdim+GR(0,1)] + b_hh[Hdim+GR(0,1)],
                  b_ih[Hdim+GR(0,2)] + b_hh[Hdim+GR(0,2)], b_ih[Hdim+GR(0,3)] + b_hh[Hdim+GR(0,3)]};
    f32x4 bzv1 = {b_ih[Hdim+GR(1,0)] + b_hh[Hdim+GR(1,0)], b_ih[Hdim+GR(1,1)] + b_hh[Hdim+GR(1,1)],
                  b_ih[Hdim+GR(1,2)] + b_hh[Hdim+GR(1,2)], b_ih[Hdim+GR(1,3)] + b_hh[Hdim+GR(1,3)]};
    f32x4 bnhv0 = {b_hh[2*Hdim+GR(0,0)], b_hh[2*Hdim+GR(0,1)], b_hh[2*Hdim+GR(0,2)], b_hh[2*Hdim+GR(0,3)]};
    f32x4 bnhv1 = {b_hh[2*Hdim+GR(1,0)], b_hh[2*Hdim+GR(1,1)], b_hh[2*Hdim+GR(1,2)], b_hh[2*Hdim+GR(1,3)]};
    f32x4 bnxv0 = {b_ih[2*Hdim+GR(0,0)], b_ih[2*Hdim+GR(0,1)], b_ih[2*Hdim+GR(0,2)], b_ih[2*Hdim+GR(0,3)]};
    f32x4 bnxv1 = {b_ih[2*Hdim+GR(1,0)], b_ih[2*Hdim+GR(1,1)], b_ih[2*Hdim+GR(1,2)], b_ih[2*Hdim+GR(1,3)]};

    float hp00 = 0.f, hp01 = 0.f, hp02 = 0.f, hp03 = 0.f;   // s=0 rows
    float hp10 = 0.f, hp11 = 0.f, hp12 = 0.f, hp13 = 0.f;   // s=1 rows

    const int kb0 = 16 * (2 * w + 0) + 4 * q;
    const int kb1 = 16 * (2 * w + 1) + 4 * q;
    const int hbase0 = (((kb0 >> 5) * 4 + ((kb0 & 31) >> 3)) * 16 + bcol) * 8 + (kb0 & 7);
    const int hbase1 = (((kb1 >> 5) * 4 + ((kb1 & 31) >> 3)) * 16 + bcol) * 8 + (kb1 & 7);

    const int e_x = tid * 4, bx = e_x >> 6, jx = e_x & 63;
    const int kx  = 128 + jx;
    const int xidx = (((kx >> 5) * 4 + ((kx & 31) >> 3)) * 16 + bx) * 8 + (kx & 7);
    const float* xsrc = &x[(size_t)(b0 + bx) * Tlen * Fdim + jx];

    __syncthreads();

#define WHF(gt, kt) (*reinterpret_cast<const f16x8*>(&WH[((((gt)*4+(kt))*4+q)*128) + (l&15)*8]))
#define WIF(gt, kt) (*reinterpret_cast<const f16x8*>(&WI[((((gt)*2+(kt))*4+q)*128) + (l&15)*8]))
#define MFMA(a, b, c) __builtin_amdgcn_mfma_f32_16x16x32_f16((a), (b), (c), 0, 0, 0)

    // ---- load 36 weight fragments once (r/z/n x s=0,1)
    f16x8 whr00 = WHF(2*w,      0), whr01 = WHF(2*w,      1), whr02 = WHF(2*w,      2), whr03 = WHF(2*w,      3);
    f16x8 whr10 = WHF(2*w+1,    0), whr11 = WHF(2*w+1,    1), whr12 = WHF(2*w+1,    2), whr13 = WHF(2*w+1,    3);
    f16x8 whz00 = WHF(8+2*w,    0), whz01 = WHF(8+2*w,    1), whz02 = WHF(8+2*w,    2), whz03 = WHF(8+2*w,    3);
    f16x8 whz10 = WHF(8+2*w+1,  0), whz11 = WHF(8+2*w+1,  1), whz12 = WHF(8+2*w+1,  2), whz13 = WHF(8+2*w+1,  3);
    f16x8 whn00 = WHF(16+2*w,   0), whn01 = WHF(16+2*w,   1), whn02 = WHF(16+2*w,   2), whn03 = WHF(16+2*w,   3);
    f16x8 whn10 = WHF(16+2*w+1, 0), whn11 = WHF(16+2*w+1, 1), whn12 = WHF(16+2*w+1, 2), whn13 = WHF(16+2*w+1, 3);
    f16x8 wir00 = WIF(2*w,      0), wir01 = WIF(2*w,      1);
    f16x8 wir10 = WIF(2*w+1,    0), wir11 = WIF(2*w+1,    1);
    f16x8 wiz00 = WIF(8+2*w,    0), wiz01 = WIF(8+2*w,    1);
    f16x8 wiz10 = WIF(8+2*w+1,  0), wiz11 = WIF(8+2*w+1,  1);
    f16x8 win00 = WIF(16+2*w,   0), win01 = WIF(16+2*w,   1);
    f16x8 win10 = WIF(16+2*w+1, 0), win11 = WIF(16+2*w+1, 1);

    // x prefetch: xp holds x(t+1) entering step t
    float4 xp = *reinterpret_cast<const float4*>(xsrc + (size_t)1 * Fdim);

    auto step = [&](const _Float16* __restrict__ Ur, _Float16* __restrict__ Uw, int t) {
        // in-loop pins: W_hh frags stay AGPR-resident, W_ih frags VGPR-resident
        asm volatile("" : "+a"(whr00), "+a"(whr01), "+a"(whr02), "+a"(whr03),
                          "+a"(whr10), "+a"(whr11), "+a"(whr12), "+a"(whr13));
        asm volatile("" : "+a"(whz00), "+a"(whz01), "+a"(whz02), "+a"(whz03),
                          "+a"(whz10), "+a"(whz11), "+a"(whz12), "+a"(whz13));
        asm volatile("" : "+a"(whn00), "+a"(whn01), "+a"(whn02), "+a"(whn03),
                          "+a"(whn10), "+a"(whn11), "+a"(whn12), "+a"(whn13));
        asm volatile("" : "+v"(wir00), "+v"(wir01), "+v"(wir10), "+v"(wir11),
                          "+v"(wiz00), "+v"(wiz01));
        asm volatile("" : "+v"(wiz10), "+v"(wiz11), "+v"(win00), "+v"(win01),
                          "+v"(win10), "+v"(win11));

        // u fragments (h: 4 tiles, x: 2 tiles)
        f16x8 ub0 = *reinterpret_cast<const f16x8*>(&Ur[((0*4+q)*16 + bcol)*8]);
        f16x8 ub1 = *reinterpret_cast<const f16x8*>(&Ur[((1*4+q)*16 + bcol)*8]);
        f16x8 ub2 = *reinterpret_cast<const f16x8*>(&Ur[((2*4+q)*16 + bcol)*8]);
        f16x8 ub3 = *reinterpret_cast<const f16x8*>(&Ur[((3*4+q)*16 + bcol)*8]);
        f16x8 ub4 = *reinterpret_cast<const f16x8*>(&Ur[((4*4+q)*16 + bcol)*8]);
        f16x8 ub5 = *reinterpret_cast<const f16x8*>(&Ur[((5*4+q)*16 + bcol)*8]);

        float4 xw = xp;                                   // x(t+1)
        if (t + 2 < Tlen)
            xp = *reinterpret_cast<const float4*>(xsrc + (size_t)(t + 2) * Fdim);

        // 6 independent h-chains (depth 4) + x tails
        f32x4 cr0 = brv0, cr1 = brv1, cz0 = bzv0, cz1 = bzv1;
        f32x4 cnh0 = bnhv0, cnh1 = bnhv1, cnx0 = bnxv0, cnx1 = bnxv1;

        cr0 = MFMA(whr00, ub0, cr0);  cr1 = MFMA(whr10, ub0, cr1);
        cz0 = MFMA(whz00, ub0, cz0);  cz1 = MFMA(whz10, ub0, cz1);
        cnh0 = MFMA(whn00, ub0, cnh0); cnh1 = MFMA(whn10, ub0, cnh1);
        cr0 = MFMA(whr01, ub1, cr0);  cr1 = MFMA(whr11, ub1, cr1);
        cz0 = MFMA(whz01, ub1, cz0);  cz1 = MFMA(whz11, ub1, cz1);
        cnh0 = MFMA(whn01, ub1, cnh0); cnh1 = MFMA(whn11, ub1, cnh1);
        cr0 = MFMA(whr02, ub2, cr0);  cr1 = MFMA(whr12, ub2, cr1);
        cz0 = MFMA(whz02, ub2, cz0);  cz1 = MFMA(whz12, ub2, cz1);
        cnh0 = MFMA(whn02, ub2, cnh0); cnh1 = MFMA(whn12, ub2, cnh1);
        cr0 = MFMA(whr03, ub3, cr0);  cr1 = MFMA(whr13, ub3, cr1);
        cz0 = MFMA(whz03, ub3, cz0);  cz1 = MFMA(whz13, ub3, cz1);
        cnh0 = MFMA(whn03, ub3, cnh0); cnh1 = MFMA(whn13, ub3, cnh1);
        cr0 = MFMA(wir00, ub4, cr0);  cr1 = MFMA(wir10, ub4, cr1);
        cz0 = MFMA(wiz00, ub4, cz0);  cz1 = MFMA(wiz10, ub4, cz1);
        cnx0 = MFMA(win00, ub4, cnx0); cnx1 = MFMA(win10, ub4, cnx1);
        cr0 = MFMA(wir01, ub5, cr0);  cr1 = MFMA(wir11, ub5, cr1);
        cz0 = MFMA(wiz01, ub5, cz0);  cz1 = MFMA(wiz11, ub5, cz1);
        cnx0 = MFMA(win01, ub5, cnx0); cnx1 = MFMA(win11, ub5, cnx1);

        // gates for 8 rows/lane
        {
            float r0 = fast_sigmoid(cr0[0]), z0 = fast_sigmoid(cz0[0]);
            float r1 = fast_sigmoid(cr0[1]), z1 = fast_sigmoid(cz0[1]);
            float r2 = fast_sigmoid(cr0[2]), z2 = fast_sigmoid(cz0[2]);
            float r3 = fast_sigmoid(cr0[3]), z3 = fast_sigmoid(cz0[3]);
            float n0 = fast_tanh(cnx0[0] + r0 * cnh0[0]);
            float n1 = fast_tanh(cnx0[1] + r1 * cnh0[1]);
            float n2 = fast_tanh(cnx0[2] + r2 * cnh0[2]);
            float n3 = fast_tanh(cnx0[3] + r3 * cnh0[3]);
            hp00 = (1.f - z0) * n0 + z0 * hp00;
            hp01 = (1.f - z1) * n1 + z1 * hp01;
            hp02 = (1.f - z2) * n2 + z2 * hp02;
            hp03 = (1.f - z3) * n3 + z3 * hp03;
        }
        {
            float r0 = fast_sigmoid(cr1[0]), z0 = fast_sigmoid(cz1[0]);
            float r1 = fast_sigmoid(cr1[1]), z1 = fast_sigmoid(cz1[1]);
            float r2 = fast_sigmoid(cr1[2]), z2 = fast_sigmoid(cz1[2]);
            float r3 = fast_sigmoid(cr1[3]), z3 = fast_sigmoid(cz1[3]);
            float n0 = fast_tanh(cnx1[0] + r0 * cnh1[0]);
            float n1 = fast_tanh(cnx1[1] + r1 * cnh1[1]);
            float n2 = fast_tanh(cnx1[2] + r2 * cnh1[2]);
            float n3 = fast_tanh(cnx1[3] + r3 * cnh1[3]);
            hp10 = (1.f - z0) * n0 + z0 * hp10;
            hp11 = (1.f - z1) * n1 + z1 * hp11;
            hp12 = (1.f - z2) * n2 + z2 * hp12;
            hp13 = (1.f - z3) * n3 + z3 * hp13;
        }

        f16x4 hq0 = {(_Float16)hp00, (_Float16)hp01, (_Float16)hp02, (_Float16)hp03};
        f16x4 hq1 = {(_Float16)hp10, (_Float16)hp11, (_Float16)hp12, (_Float16)hp13};
        *reinterpret_cast<f16x4*>(&Uw[hbase0]) = hq0;
        *reinterpret_cast<f16x4*>(&Uw[hbase1]) = hq1;

        if (t + 1 < Tlen) {
            f16x4 xq = {(_Float16)xw.x, (_Float16)xw.y, (_Float16)xw.z, (_Float16)xw.w};
            *reinterpret_cast<f16x4*>(&Uw[xidx]) = xq;
        }
        __syncthreads();
    };

    #pragma unroll 1
    for (int t = 0; t < Tlen; t += 2) {
        step(U0, U1, t);
        step(U1, U0, t + 1);
    }
    // final h(T) in U0

    // ---- epilogue MLP: hidden = relu(hT @ W1.T + b1); out = hidden @ W2.T + b2
    for (int sidx = tid; sidx < 512; sidx += NTHR) {
        int m = sidx & 31, b = sidx >> 5;
        float acc = b1[m];
        #pragma unroll 8
        for (int k = 0; k < Hdim; ++k) {
            int ui = (((k >> 5) * 4 + ((k & 31) >> 3)) * 16 + b) * 8 + (k & 7);
            acc += W1[m * Hdim + k] * (float)U0[ui];
        }
        float v = W2[m] * fmaxf(acc, 0.f);
        v += __shfl_xor(v, 1,  32);
        v += __shfl_xor(v, 2,  32);
        v += __shfl_xor(v, 4,  32);
        v += __shfl_xor(v, 8,  32);
        v += __shfl_xor(v, 16, 32);
        if (m == 0) out[b0 + b] = v + b2[0];
    }
}

extern "C" void kernel_launch(void* const* d_in, const int* in_sizes, int n_in,
                              void* d_out, int out_size, void* d_ws, size_t ws_size,
                              hipStream_t stream)
{
    const float* x    = (const float*)d_in[0];
    const float* W_ih = (const float*)d_in[1];
    const float* W_hh = (const float*)d_in[2];
    const float* b_ih = (const float*)d_in[3];
    const float* b_hh = (const float*)d_in[4];
    const float* W1   = (const float*)d_in[5];
    const float* b1   = (const float*)d_in[6];
    const float* W2   = (const float*)d_in[7];
    const float* b2   = (const float*)d_in[8];
    float* out = (float*)d_out;

    dim3 grid(NBLK), block(NTHR);
    hipLaunchKernelGGL(gru_mfma, grid, block, 0, stream,
                       x, W_ih, W_hh, b_ih, b_hh, W1, b1, W2, b2, out);
}

// Round 9
// 343.216 us; speedup vs baseline: 1.3000x; 1.3000x over previous
//
#include <hip/hip_runtime.h>
#include <math.h>

// GRUDetector: B=1024, T=512, F=64, H=128, gates (r,z,n), + MLP head (H->32->1).
// R9: R7 (331us, 1622 cyc/step) decomposes: per-SIMD issue ~724 (trans 384 +
// MFMA 180 + VALU 160) + per-CU DS service ~720 + poor overlap. Trans/VALU
// scale with batch-per-block; DS (fixed 16-col frags) does not; 192 CUs idle.
// Fix: NB=8, 128 blocks (trans/VALU per SIMD halve; DS floor amortized over
// 2x CUs) + R8's "+a" AGPR pins (in-loop) so MFMA reads A-operands natively
// from AGPR, no copy tax. R8's failure was 1 wave/SIMD, NOT the pins; here 8
// waves = 2/SIMD (waves_per_eu(2,2), 152 < 256 combined regs). Batch cols
// 8-15 compute bounded garbage (col-separable MFMA, zero-inited, never read).
// Skeleton: U dbuf, 1 barrier/step, lookahead-2 x prefetch (R7, absmax 9.8e-4).

#define Bsz  1024
#define Tlen 512
#define Fdim 64
#define Hdim 128
#define Gdim 384
#define NB   8
#define NTHR 512
#define NBLK (Bsz / NB)   // 128

typedef __attribute__((ext_vector_type(8))) _Float16 f16x8;
typedef __attribute__((ext_vector_type(4))) _Float16 f16x4;
typedef __attribute__((ext_vector_type(2))) _Float16 f16x2;
typedef __attribute__((ext_vector_type(4))) float    f32x4;

__device__ __forceinline__ float fast_sigmoid(float v) {
    return __builtin_amdgcn_rcpf(1.f + __expf(-v));
}
__device__ __forceinline__ float fast_tanh(float v) {
    return 1.f - 2.f * __builtin_amdgcn_rcpf(__expf(2.f * v) + 1.f);
}

__global__ void
__attribute__((amdgpu_flat_work_group_size(NTHR, NTHR), amdgpu_waves_per_eu(2, 2)))
gru_mfma(const float* __restrict__ x,
         const float* __restrict__ W_ih, const float* __restrict__ W_hh,
         const float* __restrict__ b_ih, const float* __restrict__ b_hh,
         const float* __restrict__ W1, const float* __restrict__ b1,
         const float* __restrict__ W2, const float* __restrict__ b2,
         float* __restrict__ out)
{
    __shared__ __align__(16) _Float16 WH[24 * 4 * 4 * 128];  // 98,304 B
    __shared__ __align__(16) _Float16 WI[24 * 2 * 4 * 128];  // 49,152 B
    __shared__ __align__(16) _Float16 U0[6 * 4 * 16 * 8];    //  6,144 B
    __shared__ __align__(16) _Float16 U1[6 * 4 * 16 * 8];    //  6,144 B  (156 KB)

    const int tid  = threadIdx.x;
    const int w    = tid >> 6;        // wave 0..7: gate rows 16w..16w+15
    const int l    = tid & 63;
    const int q    = l >> 4;
    const int bcol = l & 15;
    const int b0   = blockIdx.x * NB;

    // ---- stage W_hh, W_ih into LDS in A-fragment layout (one-time)
    for (int i = tid; i < Gdim * Hdim; i += NTHR) {
        int gr = i >> 7, k = i & 127;
        int idx = (((gr >> 4) * 4 + (k >> 5)) * 4 + ((k & 31) >> 3)) * 128
                + (gr & 15) * 8 + (k & 7);
        WH[idx] = (_Float16)W_hh[i];
    }
    for (int i = tid; i < Gdim * Fdim; i += NTHR) {
        int gr = i >> 6, k = i & 63;
        int idx = (((gr >> 4) * 2 + (k >> 5)) * 4 + ((k & 31) >> 3)) * 128
                + (gr & 15) * 8 + (k & 7);
        WI[idx] = (_Float16)W_ih[i];
    }
    // zero BOTH U buffers fully (cols 8..15 stay 0 / bounded forever)
    for (int i = tid; i < 6 * 4 * 16 * 8; i += NTHR) { U0[i] = (_Float16)0.f; U1[i] = (_Float16)0.f; }
    if (tid < NB * Fdim / 2) {   // stage x(t=0): 8 rows x 64 cols, 2 f16/thread
        int e = tid * 2, bx_ = e >> 6, j = e & 63;
        float2 xv = *reinterpret_cast<const float2*>(
            &x[((size_t)(b0 + bx_) * Tlen + 0) * Fdim + j]);
        int kk = 128 + j;
        int idx = (((kk >> 5) * 4 + ((kk & 31) >> 3)) * 16 + bx_) * 8 + (kk & 7);
        U0[idx]     = (_Float16)xv.x;
        U0[idx + 1] = (_Float16)xv.y;
    }

    // ---- per-lane biases (gate rows 16w + q*4 + j)
    float br[4], bz[4], bnh[4], bnx[4];
    #pragma unroll
    for (int j = 0; j < 4; ++j) {
        int gr = 16 * w + q * 4 + j;
        br[j]  = b_ih[gr] + b_hh[gr];
        bz[j]  = b_ih[Hdim + gr] + b_hh[Hdim + gr];
        bnh[j] = b_hh[2 * Hdim + gr];
        bnx[j] = b_ih[2 * Hdim + gr];
    }

    float hp0 = 0.f, hp1 = 0.f, hp2 = 0.f, hp3 = 0.f;

    const int kb    = 16 * w + 4 * q;
    const int hbase = (((kb >> 5) * 4 + ((kb & 31) >> 3)) * 16 + bcol) * 8 + (kb & 7);

    const bool xthr = (tid < NB * Fdim / 2);        // threads that stage x
    const int e_x = tid * 2, bx = xthr ? (e_x >> 6) : 0, jx = e_x & 63;
    const int kx  = 128 + jx;
    const int xidx = (((kx >> 5) * 4 + ((kx & 31) >> 3)) * 16 + bx) * 8 + (kx & 7);
    const float* xsrc = &x[(size_t)(b0 + bx) * Tlen * Fdim + jx];

    __syncthreads();

#define WHF(gt, kt) (*reinterpret_cast<const f16x8*>(&WH[((((gt)*4+(kt))*4+q)*128) + (l&15)*8]))
#define WIF(gt, kt) (*reinterpret_cast<const f16x8*>(&WI[((((gt)*2+(kt))*4+q)*128) + (l&15)*8]))
#define MFMA(a, b, c) __builtin_amdgcn_mfma_f32_16x16x32_f16((a), (b), (c), 0, 0, 0)

    // ---- load 18 weight fragments once (held in AGPRs via "+a" pins below)
    f16x8 whr0 = WHF(w, 0),      whr1 = WHF(w, 1),      whr2 = WHF(w, 2),      whr3 = WHF(w, 3);
    f16x8 whz0 = WHF(8 + w, 0),  whz1 = WHF(8 + w, 1),  whz2 = WHF(8 + w, 2),  whz3 = WHF(8 + w, 3);
    f16x8 whn0 = WHF(16 + w, 0), whn1 = WHF(16 + w, 1), whn2 = WHF(16 + w, 2), whn3 = WHF(16 + w, 3);
    f16x8 wir0 = WIF(w, 0),      wir1 = WIF(w, 1);
    f16x8 wiz0 = WIF(8 + w, 0),  wiz1 = WIF(8 + w, 1);
    f16x8 win0 = WIF(16 + w, 0), win1 = WIF(16 + w, 1);

    // x prefetch: xp holds x(t+1) entering step t
    float2 xp = {0.f, 0.f};
    if (xthr) xp = *reinterpret_cast<const float2*>(xsrc + (size_t)1 * Fdim);

    auto step = [&](const _Float16* __restrict__ Ur, _Float16* __restrict__ Uw, int t) {
        // in-loop AGPR pins: loop-carried opaque values -> no remat, no copies
        asm volatile("" : "+a"(whr0), "+a"(whr1), "+a"(whr2), "+a"(whr3),
                          "+a"(whz0), "+a"(whz1));
        asm volatile("" : "+a"(whz2), "+a"(whz3), "+a"(whn0), "+a"(whn1),
                          "+a"(whn2), "+a"(whn3));
        asm volatile("" : "+a"(wir0), "+a"(wir1), "+a"(wiz0), "+a"(wiz1),
                          "+a"(win0), "+a"(win1));

        // u fragments (h: 4 tiles, x: 2 tiles)
        f16x8 ub0 = *reinterpret_cast<const f16x8*>(&Ur[((0*4+q)*16 + bcol)*8]);
        f16x8 ub1 = *reinterpret_cast<const f16x8*>(&Ur[((1*4+q)*16 + bcol)*8]);
        f16x8 ub2 = *reinterpret_cast<const f16x8*>(&Ur[((2*4+q)*16 + bcol)*8]);
        f16x8 ub3 = *reinterpret_cast<const f16x8*>(&Ur[((3*4+q)*16 + bcol)*8]);
        f16x8 ub4 = *reinterpret_cast<const f16x8*>(&Ur[((4*4+q)*16 + bcol)*8]);
        f16x8 ub5 = *reinterpret_cast<const f16x8*>(&Ur[((5*4+q)*16 + bcol)*8]);

        float2 xw = xp;                                   // x(t+1)
        if (xthr && t + 2 < Tlen)
            xp = *reinterpret_cast<const float2*>(xsrc + (size_t)(t + 2) * Fdim);

        f32x4 cr  = {br[0],  br[1],  br[2],  br[3]};
        f32x4 cz  = {bz[0],  bz[1],  bz[2],  bz[3]};
        f32x4 cnh = {bnh[0], bnh[1], bnh[2], bnh[3]};
        f32x4 cnx = {bnx[0], bnx[1], bnx[2], bnx[3]};

        cr  = MFMA(whr0, ub0, cr);
        cz  = MFMA(whz0, ub0, cz);
        cnh = MFMA(whn0, ub0, cnh);
        cr  = MFMA(whr1, ub1, cr);
        cz  = MFMA(whz1, ub1, cz);
        cnh = MFMA(whn1, ub1, cnh);
        cr  = MFMA(whr2, ub2, cr);
        cz  = MFMA(whz2, ub2, cz);
        cnh = MFMA(whn2, ub2, cnh);
        cr  = MFMA(whr3, ub3, cr);
        cz  = MFMA(whz3, ub3, cz);
        cnh = MFMA(whn3, ub3, cnh);
        cr  = MFMA(wir0, ub4, cr);
        cz  = MFMA(wiz0, ub4, cz);
        cnx = MFMA(win0, ub4, cnx);
        cr  = MFMA(wir1, ub5, cr);
        cz  = MFMA(wiz1, ub5, cz);
        cnx = MFMA(win1, ub5, cnx);

        float r0 = fast_sigmoid(cr[0]), z0 = fast_sigmoid(cz[0]);
        float r1 = fast_sigmoid(cr[1]), z1 = fast_sigmoid(cz[1]);
        float r2 = fast_sigmoid(cr[2]), z2 = fast_sigmoid(cz[2]);
        float r3 = fast_sigmoid(cr[3]), z3 = fast_sigmoid(cz[3]);
        float n0 = fast_tanh(cnx[0] + r0 * cnh[0]);
        float n1 = fast_tanh(cnx[1] + r1 * cnh[1]);
        float n2 = fast_tanh(cnx[2] + r2 * cnh[2]);
        float n3 = fast_tanh(cnx[3] + r3 * cnh[3]);
        hp0 = n0 + z0 * (hp0 - n0);
        hp1 = n1 + z1 * (hp1 - n1);
        hp2 = n2 + z2 * (hp2 - n2);
        hp3 = n3 + z3 * (hp3 - n3);

        f16x4 hq = {(_Float16)hp0, (_Float16)hp1, (_Float16)hp2, (_Float16)hp3};
        *reinterpret_cast<f16x4*>(&Uw[hbase]) = hq;

        if (xthr && t + 1 < Tlen) {
            f16x2 xq = {(_Float16)xw.x, (_Float16)xw.y};
            *reinterpret_cast<f16x2*>(&Uw[xidx]) = xq;
        }
        __syncthreads();   // single barrier: Uw complete, Ur reads done
    };

    #pragma unroll 1
    for (int t = 0; t < Tlen; t += 2) {
        step(U0, U1, t);
        step(U1, U0, t + 1);
    }
    // final h(T) in U0

    // ---- epilogue MLP: hidden = relu(hT @ W1.T + b1); out = hidden @ W2.T + b2
    for (int sidx = tid; sidx < 32 * NB; sidx += NTHR) {
        int m = sidx & 31, b = sidx >> 5;
        float acc = b1[m];
        #pragma unroll 8
        for (int k = 0; k < Hdim; ++k) {
            int ui = (((k >> 5) * 4 + ((k & 31) >> 3)) * 16 + b) * 8 + (k & 7);
            acc += W1[m * Hdim + k] * (float)U0[ui];
        }
        float v = W2[m] * fmaxf(acc, 0.f);
        v += __shfl_xor(v, 1,  32);
        v += __shfl_xor(v, 2,  32);
        v += __shfl_xor(v, 4,  32);
        v += __shfl_xor(v, 8,  32);
        v += __shfl_xor(v, 16, 32);
        if (m == 0) out[b0 + b] = v + b2[0];
    }
}

extern "C" void kernel_launch(void* const* d_in, const int* in_sizes, int n_in,
                              void* d_out, int out_size, void* d_ws, size_t ws_size,
                              hipStream_t stream)
{
    const float* x    = (const float*)d_in[0];
    const float* W_ih = (const float*)d_in[1];
    const float* W_hh = (const float*)d_in[2];
    const float* b_ih = (const float*)d_in[3];
    const float* b_hh = (const float*)d_in[4];
    const float* W1   = (const float*)d_in[5];
    const float* b1   = (const float*)d_in[6];
    const float* W2   = (const float*)d_in[7];
    const float* b2   = (const float*)d_in[8];
    float* out = (float*)d_out;

    dim3 grid(NBLK), block(NTHR);
    hipLaunchKernelGGL(gru_mfma, grid, block, 0, stream,
                       x, W_ih, W_hh, b_ih, b_hh, W1, b1, W2, b2, out);
}